// Round 12
// baseline (88.614 us; speedup 1.0000x reference)
//
#include <hip/hip_runtime.h>
#include <math.h>

// Chamfer p-norm loss (P=5), B=8, N=M=4096, C=3.
// R20 = R19 (banked best, 86.2us: single kernel, LDS pair-table, reg-dbuf
// pipeline) with QPT 4->8. Rationale: across all counter-exposed variants,
// runtime ~ VALU_busy + ~18us (R14 20+18, R15 30+18, R16 26+21, R11 22+18);
// the +18 survived 7 falsifications (memory paths, occupancy, atomics),
// but VALU-busy itself tracks runtime 1:1 and is ~2x the core math —
// the excess is per-thread overhead (staging, 256 buffer reads, group
// bookkeeping, rescan, addressing) that amortizes over queries/thread.
// QPT=8: same 256 LDS reads/thread now feed 8 queries; total VALU work
// -30%; ILP (8 independent chains) substitutes for TLP at 2 blocks/CU.
// Only index derivations change vs R19 (NTILE=32, TILEQ=2048, tq =
// dir*16+b*2+t2; finalize fans in 2 psums per (b,dir)); all arithmetic
// (staging h chain, score chain, strict-< group track, descending
// smallest-j rescan, key packing) byte-identical -> absmax 0.
// Kept lessons: NO __threadfence (R9: per-wave L2 wb/inv ~100us);
// __syncthreads' mandatory vmcnt(0) = release for atomics; AGENT-scope
// atomic loads (sc bypass) = acquire for tab/psum. Counter init in
// poisoned ws: CANARY word (never written) holds the fill value; "last"
// test old==canary+(n-1); finalizer restores counters to canary.
// Keys: complemented (score<<32|j), atomicMax; poison/zeros < any real key.

#define BQ      256
#define QPT     8             // queries per thread
#define SPLITS  16
#define CH      256           // refs per split-block
#define GS      8             // refs per tracked group
#define NG      (CH / GS)     // 32 groups
#define BIGOFF  64.0f         // folds into h: scores stay in (64-|q|^2/2, ~200) > 0
#define NQTOT   65536         // 2 dirs * 8 batches * 4096 queries
#define NTILE   32            // query tiles of 2048
#define TILEQ   2048          // queries per tile (BQ * QPT)

typedef float f32x2 __attribute__((ext_vector_type(2)));
typedef float f32x4 __attribute__((ext_vector_type(4)));

static __device__ __forceinline__ f32x2 mk2(float s) { f32x2 v; v.x = s; v.y = s; return v; }
static __device__ __forceinline__ f32x2 fma2(f32x2 a, f32x2 b, f32x2 c) {
    return __builtin_elementwise_fma(a, b, c);
}
__device__ __forceinline__ unsigned int float_ord(float f) {
    unsigned int u = __float_as_uint(f);
    return (u & 0x80000000u) ? ~u : (u | 0x80000000u);
}

// ws layout (fast path):
//   [0,64)      legacy acc area (fallback path only)
//   [128,132)   CANARY u32 — never written; holds the uniform fill value
//   [192,196)   gcnt u32  — global tile-completion counter (starts at canary)
//   [256,384)   tcnt[32] u32 — per-tile split counters (start at canary)
//   [1024,1152) psum[32] f32 — per-tile partial sums
//   [4096, 4096+512K) tab u64[NQTOT] — complemented (score|j) keys, atomicMax
#define WS_ACC    0
#define WS_CANARY 128
#define WS_GCNT   192
#define WS_TCNT   256
#define WS_PSUM   1024
#define WS_TAB    4096

// compute one GS-ref group (4 pairs) from a register buffer; bit-identical
// score chain; exact-commutative mins; strict-< earliest-group update.
#define COMPUTE_GROUP(BUF, G)                                              \
  {                                                                        \
    float mloc[QPT];                                                       \
    _Pragma("unroll")                                                      \
    for (int k4 = 0; k4 < 4; ++k4) {                                       \
      const f32x4 a = BUF[2 * k4];          /* rx0,rx1,ry0,ry1 */          \
      const f32x4 c = BUF[2 * k4 + 1];      /* rz0,rz1,h0,h1  */           \
      const f32x2 rx = __builtin_shufflevector(a, a, 0, 1);                \
      const f32x2 ry = __builtin_shufflevector(a, a, 2, 3);                \
      const f32x2 rz = __builtin_shufflevector(c, c, 0, 1);                \
      const f32x2 h2 = __builtin_shufflevector(c, c, 2, 3);                \
      _Pragma("unroll")                                                    \
      for (int qk = 0; qk < QPT; ++qk) {                                   \
        const f32x2 s = fma2(nqx[qk], rx,                                  \
                        fma2(nqy[qk], ry, fma2(nqz[qk], rz, h2)));         \
        if (k4 == 0) mloc[qk] = fminf(s.x, s.y);                           \
        else         mloc[qk] = fminf(fminf(mloc[qk], s.x), s.y);          \
      }                                                                    \
    }                                                                      \
    _Pragma("unroll")                                                      \
    for (int qk = 0; qk < QPT; ++qk) {                                     \
      const bool cc = mloc[qk] < best[qk];  /* strict <: earliest group */ \
      best[qk] = cc ? mloc[qk] : best[qk];                                 \
      bg[qk]   = cc ? (G) : bg[qk];                                        \
    }                                                                      \
  }

// ---- fused scan + per-tile gather + finalize:
// grid = 32 query-tiles (2048 q each) x 16 ref-splits = 512 blocks
__global__ __launch_bounds__(BQ, 2) void chamfer_fused_r20(
    const float* __restrict__ x, const float* __restrict__ y,
    unsigned long long* __restrict__ tab,
    unsigned int* __restrict__ tcnt, unsigned int* __restrict__ gcnt,
    const unsigned int* __restrict__ canary_p,
    float* __restrict__ psum, float* __restrict__ out)
{
    __shared__ f32x4 sref[CH];  // pair layout: [2p]=(rx0,rx1,ry0,ry1) [2p+1]=(rz0,rz1,h0,h1)
    __shared__ float red[4];
    __shared__ int s_flag;

    const int bid   = blockIdx.x;
    const int split = bid & (SPLITS - 1);
    const int tq    = bid >> 4;          // 0..31 = dir*16 + b*2 + t2
    const int dir   = tq >> 4;
    const int b     = (tq >> 1) & 7;
    const int t2    = tq & 1;

    const unsigned int canary = *canary_p;  // uniform fill value (0xAA.. or 0)

    const float* Q; const float* R;
    if (dir == 0) { Q = x + (size_t)b * 4096 * 3; R = y + (size_t)b * 4096 * 3; }
    else          { Q = y + (size_t)b * 4096 * 3; R = x + (size_t)b * 4096 * 3; }

    const int tid = threadIdx.x;

    // stage this block's 128 ref-pairs into LDS (pair layout, h folded);
    // h chain bit-identical to the rescan's (R10-proven).
    if (tid < CH / 2) {
        const float* rp = R + (size_t)(split * CH + 2 * tid) * 3;
        const float f0 = rp[0], f1 = rp[1], f2 = rp[2];
        const float f3 = rp[3], f4 = rp[4], f5 = rp[5];
        const float h0 = fmaf(0.5f * f0, f0, fmaf(0.5f * f1, f1, fmaf(0.5f * f2, f2, BIGOFF)));
        const float h1 = fmaf(0.5f * f3, f3, fmaf(0.5f * f4, f4, fmaf(0.5f * f5, f5, BIGOFF)));
        f32x4 e0; e0.x = f0; e0.y = f3; e0.z = f1; e0.w = f4;
        f32x4 e1; e1.x = f2; e1.y = f5; e1.z = h0; e1.w = h1;
        sref[2 * tid]     = e0;
        sref[2 * tid + 1] = e1;
    }

    // 8 scalar queries per thread, kept ONLY as negated pk splats
    // (rescan recovers q via bit-exact sign flip).
    f32x2 nqx[QPT], nqy[QPT], nqz[QPT];
    #pragma unroll
    for (int qk = 0; qk < QPT; ++qk) {
        const int ql = t2 * TILEQ + qk * 256 + tid;
        nqx[qk] = mk2(-Q[ql * 3 + 0]);
        nqy[qk] = mk2(-Q[ql * 3 + 1]);
        nqz[qk] = mk2(-Q[ql * 3 + 2]);
    }
    __syncthreads();

    float best[QPT]; int bg[QPT];
    #pragma unroll
    for (int qk = 0; qk < QPT; ++qk) { best[qk] = 3.4e38f; bg[qk] = 0; }

    // ---- register double-buffered group pipeline over LDS (R19-proven):
    // prefetch group g+1 while computing g; final prefetch wraps to group 0
    // (in-bounds, value never consumed). Broadcast uniform-address ds_reads:
    // conflict-free.
    f32x4 bufA[8], bufB[8];
    #pragma unroll
    for (int i = 0; i < 8; ++i) bufA[i] = sref[i];

    #pragma unroll 1
    for (int g = 0; g < NG; g += 2) {
        #pragma unroll
        for (int i = 0; i < 8; ++i) bufB[i] = sref[(g + 1) * 8 + i];
        COMPUTE_GROUP(bufA, g)
        const int gpre = (g + 2) & (NG - 1);   // wraps to 0 on last iter
        #pragma unroll
        for (int i = 0; i < 8; ++i) bufA[i] = sref[gpre * 8 + i];
        COMPUTE_GROUP(bufB, g + 1)
    }

    // exact index: re-scan winning GS-ref group from global R (L2-hot);
    // bit-identical fma/h chain reproduces the packed-path score exactly.
    #pragma unroll
    for (int qk = 0; qk < QPT; ++qk) {
        const float bscore = best[qk];
        const float qx = -nqx[qk].x;   // bit-exact double sign-flip
        const float qy = -nqy[qk].x;
        const float qz = -nqz[qk].x;
        const int basej = split * CH + bg[qk] * GS;
        int bj = basej;
        #pragma unroll
        for (int j = GS - 1; j >= 0; --j) {      // descending: smallest j wins
            const float* rp = R + (size_t)(basej + j) * 3;
            const float rx = rp[0], ry = rp[1], rz = rp[2];
            const float h = fmaf(0.5f * rx, rx, fmaf(0.5f * ry, ry, fmaf(0.5f * rz, rz, BIGOFF)));
            const float s = fmaf(-qx, rx, fmaf(-qy, ry, fmaf(-qz, rz, h)));
            if (s == bscore) bj = basej + j;
        }
        const size_t qidx = (size_t)tq * TILEQ + qk * 256 + tid;
        // complemented key: max(~packed) == min(packed); 0xAA poison and
        // fresh zeros are both < any real key -> no init required.
        const unsigned long long key =
            ~(((unsigned long long)__float_as_uint(bscore) << 32) | (unsigned int)bj);
        atomicMax(&tab[qidx], key);   // fire-and-forget (return unused)
    }

    // ---- per-tile completion handshake: 16th split-block gathers the tile.
    // NO __threadfence (R9 lesson). __syncthreads' compiler-mandated
    // s_waitcnt vmcnt(0) drains every wave's atomicMax to the coherent
    // point before tid0's counter bump.
    __syncthreads();
    if (tid == 0) {
        const unsigned int old = atomicAdd(&tcnt[tq], 1u);
        s_flag = (old == canary + (SPLITS - 1));
    }
    __syncthreads();
    if (!s_flag) return;

    // ---- gather this tile's 2048 queries (8/thread). tab MUST be read with
    // AGENT-scope atomic loads (sc cache-bypass): local L2 may hold stale
    // poison lines; atomicMax updated the coherent point only (R4 lesson).
    float sthr = 0.0f;
    #pragma unroll
    for (int k = 0; k < QPT; ++k) {
        const int gq = tq * TILEQ + k * 256 + tid;
        const int q  = t2 * TILEQ + k * 256 + tid;
        const unsigned long long w =
            ~__hip_atomic_load(&tab[gq], __ATOMIC_RELAXED, __HIP_MEMORY_SCOPE_AGENT);
        const int j = (int)(unsigned int)w;
        const float dx = Q[q * 3 + 0] - R[(size_t)j * 3 + 0];
        const float dy = Q[q * 3 + 1] - R[(size_t)j * 3 + 1];
        const float dz = Q[q * 3 + 2] - R[(size_t)j * 3 + 2];
        const float ax = fabsf(dx), ay = fabsf(dy), az = fabsf(dz);
        const float ax2 = ax * ax, ay2 = ay * ay, az2 = az * az;
        sthr += ax2 * ax2 * ax + ay2 * ay2 * ay + az2 * az2 * az;
    }
    #pragma unroll
    for (int off = 32; off > 0; off >>= 1) sthr += __shfl_down(sthr, off, 64);
    const int wid = tid >> 6, lane = tid & 63;
    if (lane == 0) red[wid] = sthr;
    __syncthreads();

    if (tid == 0) {
        __hip_atomic_store(&psum[tq], red[0] + red[1] + red[2] + red[3],
                           __ATOMIC_RELAXED, __HIP_MEMORY_SCOPE_AGENT);
        // order psum store before gcnt bump: drain to coherent point (1 instr,
        // single thread — NOT a threadfence, no L2 writeback).
        asm volatile("s_waitcnt vmcnt(0)" ::: "memory");
        const unsigned int old = atomicAdd(gcnt, 1u);
        s_flag = (old == canary + (NTILE - 1));
    }
    __syncthreads();
    if (!s_flag) return;

    // ---- globally-last tile: finalize. x^0.2 via exp2/log2 (rel err ~1e-5).
    // psum read via AGENT-scope bypass loads: counter RMW return proved all
    // writers' stores performed at the coherent point before ours.
    if (tid < 64) {
        float v = 0.0f;
        if (tid < 16) {
            const int fb = tid >> 1, fdir = tid & 1;  // slot = b*2+dir
            float a = 0.0f;
            #pragma unroll
            for (int t = 0; t < 2; ++t)
                a += __hip_atomic_load(&psum[fdir * 16 + fb * 2 + t],
                                       __ATOMIC_RELAXED, __HIP_MEMORY_SCOPE_AGENT);
            v = exp2f(0.2f * log2f(a));
        }
        #pragma unroll
        for (int off = 8; off > 0; off >>= 1) v += __shfl_down(v, off, 64);
        if (tid == 0) out[0] = v * 0.125f;            // mean over B=8
    }
    // restore counters to the canary value so a non-repoisoned rerun is
    // still correct (tab is idempotent under atomicMax with same inputs).
    if (tid < NTILE)
        __hip_atomic_store(&tcnt[tid], canary, __ATOMIC_RELAXED, __HIP_MEMORY_SCOPE_AGENT);
    if (tid == 0)
        __hip_atomic_store(gcnt, canary, __ATOMIC_RELAXED, __HIP_MEMORY_SCOPE_AGENT);
}

// ================= round-2 proven fallback (generic sizes) =================
__global__ __launch_bounds__(BQ) void chamfer_nn_split_kernel(
    const float* __restrict__ x, const float* __restrict__ y,
    unsigned long long* __restrict__ packed, int N, int M)
{
    __shared__ float4 sref[1024];
    const int bid = blockIdx.x, split = bid & 3, qb = bid >> 2;
    const int tile = qb & 15, dir = (qb >> 4) & 1, b = qb >> 5;
    const float* Q; const float* R;
    if (dir == 0) { Q = x + (size_t)b * N * 3; R = y + (size_t)b * M * 3; }
    else          { Q = y + (size_t)b * M * 3; R = x + (size_t)b * N * 3; }
    const int tid = threadIdx.x, q = tile * BQ + tid, base = split * 1024;
    for (int j = tid; j < 1024; j += BQ) {
        const float rx = R[(size_t)(base + j) * 3 + 0];
        const float ry = R[(size_t)(base + j) * 3 + 1];
        const float rz = R[(size_t)(base + j) * 3 + 2];
        sref[j] = make_float4(rx, ry, rz, 0.5f * (rx * rx + ry * ry + rz * rz));
    }
    __syncthreads();
    const float qx = Q[q * 3 + 0], qy = Q[q * 3 + 1], qz = Q[q * 3 + 2];
    float best = 3.4e38f; int bestj = base;
    #pragma unroll 8
    for (int j = 0; j < 1024; ++j) {
        const float4 r = sref[j];
        float t = __fmaf_rn(-qx, r.x, r.w);
        t = __fmaf_rn(-qy, r.y, t);
        t = __fmaf_rn(-qz, r.z, t);
        const bool c = t < best;
        best = c ? t : best; bestj = c ? (base + j) : bestj;
    }
    const size_t idx = ((size_t)dir * 8 + b) * (size_t)N + q;
    atomicMin(&packed[idx], ((unsigned long long)float_ord(best) << 32) | (unsigned int)bestj);
}

__global__ __launch_bounds__(BQ) void chamfer_gather_kernel(
    const float* __restrict__ x, const float* __restrict__ y,
    const unsigned long long* __restrict__ packed,
    float* __restrict__ acc, int N, int M)
{
    __shared__ float red[4];
    const int tid = threadIdx.x;
    const size_t gq = (size_t)blockIdx.x * BQ + tid;
    const int dir = (int)(gq / ((size_t)8 * N));
    const size_t rem = gq - (size_t)dir * 8 * N;
    const int b = (int)(rem / N), q = (int)(rem - (size_t)b * N);
    const float* Q; const float* R;
    if (dir == 0) { Q = x + (size_t)b * N * 3; R = y + (size_t)b * M * 3; }
    else          { Q = y + (size_t)b * M * 3; R = x + (size_t)b * N * 3; }
    const int j = (int)(unsigned int)packed[gq];
    const float dx = Q[q * 3 + 0] - R[(size_t)j * 3 + 0];
    const float dy = Q[q * 3 + 1] - R[(size_t)j * 3 + 1];
    const float dz = Q[q * 3 + 2] - R[(size_t)j * 3 + 2];
    const float ax = fabsf(dx), ay = fabsf(dy), az = fabsf(dz);
    const float ax2 = ax * ax, ay2 = ay * ay, az2 = az * az;
    float s = ax2 * ax2 * ax + ay2 * ay2 * ay + az2 * az2 * az;
    #pragma unroll
    for (int off = 32; off > 0; off >>= 1) s += __shfl_down(s, off, 64);
    const int wid = tid >> 6, lane = tid & 63;
    if (lane == 0) red[wid] = s;
    __syncthreads();
    if (tid == 0) atomicAdd(&acc[b * 2 + dir], red[0] + red[1] + red[2] + red[3]);
}

__global__ void chamfer_finalize_kernel(const float* __restrict__ acc,
                                        float* __restrict__ out)
{
    if (threadIdx.x == 0 && blockIdx.x == 0) {
        float total = 0.0f;
        #pragma unroll
        for (int i = 0; i < 16; ++i) total += powf(acc[i], 0.2f);
        *out = total * 0.125f;
    }
}

extern "C" void kernel_launch(void* const* d_in, const int* in_sizes, int n_in,
                              void* d_out, int out_size, void* d_ws, size_t ws_size,
                              hipStream_t stream)
{
    const float* x = (const float*)d_in[0];
    const float* y = (const float*)d_in[1];
    float* out = (float*)d_out;
    const int N = in_sizes[0] / 24;  // B=8, C=3
    const int M = in_sizes[1] / 24;

    const size_t needed = WS_TAB + (size_t)NQTOT * 8;  // ~528 KB

    if (N == 4096 && M == 4096 && ws_size >= needed) {
        unsigned char* ws = (unsigned char*)d_ws;
        unsigned long long* tab = (unsigned long long*)(ws + WS_TAB);
        unsigned int* tcnt = (unsigned int*)(ws + WS_TCNT);
        unsigned int* gcnt = (unsigned int*)(ws + WS_GCNT);
        const unsigned int* canary = (const unsigned int*)(ws + WS_CANARY);
        float* psum = (float*)(ws + WS_PSUM);
        chamfer_fused_r20<<<NTILE * SPLITS, BQ, 0, stream>>>(
            x, y, tab, tcnt, gcnt, canary, psum, out);
    } else {
        // round-2 proven path
        unsigned char* ws = (unsigned char*)d_ws;
        float* acc = (float*)ws;
        unsigned long long* ptab = (unsigned long long*)(ws + 4096);
        const size_t nQ = (size_t)2 * 8 * N;
        hipMemsetAsync(acc, 0, 64, stream);
        hipMemsetAsync(ptab, 0xFF, nQ * 8, stream);
        chamfer_nn_split_kernel<<<(int)(nQ / BQ) * 4, BQ, 0, stream>>>(x, y, ptab, N, M);
        chamfer_gather_kernel<<<(int)(nQ / BQ), BQ, 0, stream>>>(x, y, ptab, acc, N, M);
        chamfer_finalize_kernel<<<1, 64, 0, stream>>>(acc, out);
    }
}

// Round 13
// 84.879 us; speedup vs baseline: 1.0440x; 1.0440x over previous
//
#include <hip/hip_runtime.h>
#include <math.h>

// Chamfer p-norm loss (P=5), B=8, N=M=4096, C=3.
// R21 = R19 VERBATIM REVERT (session best: 86.18us, absmax 0.0).
// R20 (QPT=8) was neutral-to-worse (88.6; fused 39.9 unchanged) — final
// falsification of the amortizable-overhead theory. Ledger: nine
// structurally distinct scan variants (QPT 2/4/8; LDS/L1-vector/SMEM-
// scalar reads; 2/4/8 waves/SIMD; dbuf on/off; atomicMax vs plain-store
// publish; atomic timing spread) ALL land the scan in [38,48]us with
// VALU-busy ~20us. Work is fixed (268M exact scores, computed once each);
// core-math floor ~8us; residual ~18us survived 7 falsifications.
// Structural floor: fill 40us (harness re-poison, 83% HBM write peak,
// untouchable) + scan ~40us (empirical floor of exact-NN on this chip
// without fp32 MFMA, which CDNA4 lacks; bf16 MFMA breaks bit-exact
// tie-breaks) + ~5us graph nodes ~ 85-86us = R19's measured 86.18.
// Structure: single kernel; per-block 4KB LDS pair-table (R10 staging,
// h folded); reg-dbuf group pipeline (R14); group-track strict-< +
// descending smallest-j rescan; complemented-key atomicMax publish;
// per-tile 16th-block gather; globally-last finalize.
// Kept lessons: NO __threadfence (R9: per-wave L2 wb/inv ~100us);
// __syncthreads' mandatory vmcnt(0) = release for atomics; AGENT-scope
// atomic loads (sc bypass) = acquire for tab/psum. Counter init in
// poisoned ws: CANARY word (never written) holds the fill value; "last"
// test old==canary+(n-1); finalizer restores counters to canary.
// Keys: complemented (score<<32|j), atomicMax; poison/zeros < any real key.

#define BQ      256
#define QPT     4             // queries per thread
#define SPLITS  16
#define CH      256           // refs per split-block
#define GS      8             // refs per tracked group
#define NG      (CH / GS)     // 32 groups
#define BIGOFF  64.0f         // folds into h: scores stay in (64-|q|^2/2, ~200) > 0
#define NQTOT   65536         // 2 dirs * 8 batches * 4096 queries
#define NTILE   64            // query tiles of 1024
#define TILEQ   1024          // queries per tile (BQ * QPT)

typedef float f32x2 __attribute__((ext_vector_type(2)));
typedef float f32x4 __attribute__((ext_vector_type(4)));

static __device__ __forceinline__ f32x2 mk2(float s) { f32x2 v; v.x = s; v.y = s; return v; }
static __device__ __forceinline__ f32x2 fma2(f32x2 a, f32x2 b, f32x2 c) {
    return __builtin_elementwise_fma(a, b, c);
}
__device__ __forceinline__ unsigned int float_ord(float f) {
    unsigned int u = __float_as_uint(f);
    return (u & 0x80000000u) ? ~u : (u | 0x80000000u);
}

// ws layout (fast path):
//   [0,64)      legacy acc area (fallback path only)
//   [128,132)   CANARY u32 — never written; holds the uniform fill value
//   [192,196)   gcnt u32  — global tile-completion counter (starts at canary)
//   [256,512)   tcnt[64] u32 — per-tile split counters (start at canary)
//   [1024,1280) psum[64] f32 — per-tile partial sums
//   [4096, 4096+512K) tab u64[NQTOT] — complemented (score|j) keys, atomicMax
#define WS_ACC    0
#define WS_CANARY 128
#define WS_GCNT   192
#define WS_TCNT   256
#define WS_PSUM   1024
#define WS_TAB    4096

// compute one GS-ref group (4 pairs) from a register buffer; bit-identical
// score chain; exact-commutative mins; strict-< earliest-group update.
#define COMPUTE_GROUP(BUF, G)                                              \
  {                                                                        \
    float mloc[QPT];                                                       \
    _Pragma("unroll")                                                      \
    for (int k4 = 0; k4 < 4; ++k4) {                                       \
      const f32x4 a = BUF[2 * k4];          /* rx0,rx1,ry0,ry1 */          \
      const f32x4 c = BUF[2 * k4 + 1];      /* rz0,rz1,h0,h1  */           \
      const f32x2 rx = __builtin_shufflevector(a, a, 0, 1);                \
      const f32x2 ry = __builtin_shufflevector(a, a, 2, 3);                \
      const f32x2 rz = __builtin_shufflevector(c, c, 0, 1);                \
      const f32x2 h2 = __builtin_shufflevector(c, c, 2, 3);                \
      _Pragma("unroll")                                                    \
      for (int qk = 0; qk < QPT; ++qk) {                                   \
        const f32x2 s = fma2(nqx[qk], rx,                                  \
                        fma2(nqy[qk], ry, fma2(nqz[qk], rz, h2)));         \
        if (k4 == 0) mloc[qk] = fminf(s.x, s.y);                           \
        else         mloc[qk] = fminf(fminf(mloc[qk], s.x), s.y);          \
      }                                                                    \
    }                                                                      \
    _Pragma("unroll")                                                      \
    for (int qk = 0; qk < QPT; ++qk) {                                     \
      const bool cc = mloc[qk] < best[qk];  /* strict <: earliest group */ \
      best[qk] = cc ? mloc[qk] : best[qk];                                 \
      bg[qk]   = cc ? (G) : bg[qk];                                        \
    }                                                                      \
  }

// ---- fused scan + per-tile gather + finalize:
// grid = 64 query-tiles (1024 q each) x 16 ref-splits = 1024 blocks
__global__ __launch_bounds__(BQ, 4) void chamfer_fused_r21(
    const float* __restrict__ x, const float* __restrict__ y,
    unsigned long long* __restrict__ tab,
    unsigned int* __restrict__ tcnt, unsigned int* __restrict__ gcnt,
    const unsigned int* __restrict__ canary_p,
    float* __restrict__ psum, float* __restrict__ out)
{
    __shared__ f32x4 sref[CH];  // pair layout: [2p]=(rx0,rx1,ry0,ry1) [2p+1]=(rz0,rz1,h0,h1)
    __shared__ float red[4];
    __shared__ int s_flag;

    const int bid   = blockIdx.x;
    const int split = bid & (SPLITS - 1);
    const int tq    = bid >> 4;          // 0..63 = dir*32 + b*4 + t4
    const int dir   = tq >> 5;
    const int b     = (tq >> 2) & 7;
    const int t4    = tq & 3;

    const unsigned int canary = *canary_p;  // uniform fill value (0xAA.. or 0)

    const float* Q; const float* R;
    if (dir == 0) { Q = x + (size_t)b * 4096 * 3; R = y + (size_t)b * 4096 * 3; }
    else          { Q = y + (size_t)b * 4096 * 3; R = x + (size_t)b * 4096 * 3; }

    const int tid = threadIdx.x;

    // stage this block's 128 ref-pairs into LDS (pair layout, h folded);
    // h chain bit-identical to the rescan's (R10-proven).
    if (tid < CH / 2) {
        const float* rp = R + (size_t)(split * CH + 2 * tid) * 3;
        const float f0 = rp[0], f1 = rp[1], f2 = rp[2];
        const float f3 = rp[3], f4 = rp[4], f5 = rp[5];
        const float h0 = fmaf(0.5f * f0, f0, fmaf(0.5f * f1, f1, fmaf(0.5f * f2, f2, BIGOFF)));
        const float h1 = fmaf(0.5f * f3, f3, fmaf(0.5f * f4, f4, fmaf(0.5f * f5, f5, BIGOFF)));
        f32x4 e0; e0.x = f0; e0.y = f3; e0.z = f1; e0.w = f4;
        f32x4 e1; e1.x = f2; e1.y = f5; e1.z = h0; e1.w = h1;
        sref[2 * tid]     = e0;
        sref[2 * tid + 1] = e1;
    }

    // 4 scalar queries per thread, kept ONLY as negated pk splats
    // (rescan recovers q via bit-exact sign flip).
    f32x2 nqx[QPT], nqy[QPT], nqz[QPT];
    #pragma unroll
    for (int qk = 0; qk < QPT; ++qk) {
        const int ql = t4 * TILEQ + qk * 256 + tid;
        nqx[qk] = mk2(-Q[ql * 3 + 0]);
        nqy[qk] = mk2(-Q[ql * 3 + 1]);
        nqz[qk] = mk2(-Q[ql * 3 + 2]);
    }
    __syncthreads();

    float best[QPT]; int bg[QPT];
    #pragma unroll
    for (int qk = 0; qk < QPT; ++qk) { best[qk] = 3.4e38f; bg[qk] = 0; }

    // ---- register double-buffered group pipeline over LDS (R14 pipeline,
    // R10 staging): prefetch group g+1 while computing g; final prefetch
    // wraps to group 0 (in-bounds, value never consumed). Broadcast
    // uniform-address ds_reads: conflict-free.
    f32x4 bufA[8], bufB[8];
    #pragma unroll
    for (int i = 0; i < 8; ++i) bufA[i] = sref[i];

    #pragma unroll 1
    for (int g = 0; g < NG; g += 2) {
        #pragma unroll
        for (int i = 0; i < 8; ++i) bufB[i] = sref[(g + 1) * 8 + i];
        COMPUTE_GROUP(bufA, g)
        const int gpre = (g + 2) & (NG - 1);   // wraps to 0 on last iter
        #pragma unroll
        for (int i = 0; i < 8; ++i) bufA[i] = sref[gpre * 8 + i];
        COMPUTE_GROUP(bufB, g + 1)
    }

    // exact index: re-scan winning GS-ref group from global R (L2-hot);
    // bit-identical fma/h chain reproduces the packed-path score exactly.
    #pragma unroll
    for (int qk = 0; qk < QPT; ++qk) {
        const float bscore = best[qk];
        const float qx = -nqx[qk].x;   // bit-exact double sign-flip
        const float qy = -nqy[qk].x;
        const float qz = -nqz[qk].x;
        const int basej = split * CH + bg[qk] * GS;
        int bj = basej;
        #pragma unroll
        for (int j = GS - 1; j >= 0; --j) {      // descending: smallest j wins
            const float* rp = R + (size_t)(basej + j) * 3;
            const float rx = rp[0], ry = rp[1], rz = rp[2];
            const float h = fmaf(0.5f * rx, rx, fmaf(0.5f * ry, ry, fmaf(0.5f * rz, rz, BIGOFF)));
            const float s = fmaf(-qx, rx, fmaf(-qy, ry, fmaf(-qz, rz, h)));
            if (s == bscore) bj = basej + j;
        }
        const size_t qidx = (size_t)tq * TILEQ + qk * 256 + tid;
        // complemented key: max(~packed) == min(packed); 0xAA poison and
        // fresh zeros are both < any real key -> no init required.
        const unsigned long long key =
            ~(((unsigned long long)__float_as_uint(bscore) << 32) | (unsigned int)bj);
        atomicMax(&tab[qidx], key);   // fire-and-forget (return unused)
    }

    // ---- per-tile completion handshake: 16th split-block gathers the tile.
    // NO __threadfence (R9 lesson). __syncthreads' compiler-mandated
    // s_waitcnt vmcnt(0) drains every wave's atomicMax to the coherent
    // point before tid0's counter bump.
    __syncthreads();
    if (tid == 0) {
        const unsigned int old = atomicAdd(&tcnt[tq], 1u);
        s_flag = (old == canary + (SPLITS - 1));
    }
    __syncthreads();
    if (!s_flag) return;

    // ---- gather this tile's 1024 queries (4/thread). tab MUST be read with
    // AGENT-scope atomic loads (sc cache-bypass): local L2 may hold stale
    // poison lines; atomicMax updated the coherent point only (R4 lesson).
    float sthr = 0.0f;
    #pragma unroll
    for (int k = 0; k < QPT; ++k) {
        const int gq = tq * TILEQ + k * 256 + tid;
        const int q  = t4 * TILEQ + k * 256 + tid;
        const unsigned long long w =
            ~__hip_atomic_load(&tab[gq], __ATOMIC_RELAXED, __HIP_MEMORY_SCOPE_AGENT);
        const int j = (int)(unsigned int)w;
        const float dx = Q[q * 3 + 0] - R[(size_t)j * 3 + 0];
        const float dy = Q[q * 3 + 1] - R[(size_t)j * 3 + 1];
        const float dz = Q[q * 3 + 2] - R[(size_t)j * 3 + 2];
        const float ax = fabsf(dx), ay = fabsf(dy), az = fabsf(dz);
        const float ax2 = ax * ax, ay2 = ay * ay, az2 = az * az;
        sthr += ax2 * ax2 * ax + ay2 * ay2 * ay + az2 * az2 * az;
    }
    #pragma unroll
    for (int off = 32; off > 0; off >>= 1) sthr += __shfl_down(sthr, off, 64);
    const int wid = tid >> 6, lane = tid & 63;
    if (lane == 0) red[wid] = sthr;
    __syncthreads();

    if (tid == 0) {
        __hip_atomic_store(&psum[tq], red[0] + red[1] + red[2] + red[3],
                           __ATOMIC_RELAXED, __HIP_MEMORY_SCOPE_AGENT);
        // order psum store before gcnt bump: drain to coherent point (1 instr,
        // single thread — NOT a threadfence, no L2 writeback).
        asm volatile("s_waitcnt vmcnt(0)" ::: "memory");
        const unsigned int old = atomicAdd(gcnt, 1u);
        s_flag = (old == canary + (NTILE - 1));
    }
    __syncthreads();
    if (!s_flag) return;

    // ---- globally-last tile: finalize. x^0.2 via exp2/log2 (rel err ~1e-5).
    // psum read via AGENT-scope bypass loads: counter RMW return proved all
    // writers' stores performed at the coherent point before ours.
    if (tid < 64) {
        float v = 0.0f;
        if (tid < 16) {
            const int fb = tid >> 1, fdir = tid & 1;  // slot = b*2+dir
            float a = 0.0f;
            #pragma unroll
            for (int t = 0; t < 4; ++t)
                a += __hip_atomic_load(&psum[fdir * 32 + fb * 4 + t],
                                       __ATOMIC_RELAXED, __HIP_MEMORY_SCOPE_AGENT);
            v = exp2f(0.2f * log2f(a));
        }
        #pragma unroll
        for (int off = 8; off > 0; off >>= 1) v += __shfl_down(v, off, 64);
        if (tid == 0) out[0] = v * 0.125f;            // mean over B=8
    }
    // restore counters to the canary value so a non-repoisoned rerun is
    // still correct (tab is idempotent under atomicMax with same inputs).
    if (tid < NTILE)
        __hip_atomic_store(&tcnt[tid], canary, __ATOMIC_RELAXED, __HIP_MEMORY_SCOPE_AGENT);
    if (tid == 0)
        __hip_atomic_store(gcnt, canary, __ATOMIC_RELAXED, __HIP_MEMORY_SCOPE_AGENT);
}

// ================= round-2 proven fallback (generic sizes) =================
__global__ __launch_bounds__(BQ) void chamfer_nn_split_kernel(
    const float* __restrict__ x, const float* __restrict__ y,
    unsigned long long* __restrict__ packed, int N, int M)
{
    __shared__ float4 sref[1024];
    const int bid = blockIdx.x, split = bid & 3, qb = bid >> 2;
    const int tile = qb & 15, dir = (qb >> 4) & 1, b = qb >> 5;
    const float* Q; const float* R;
    if (dir == 0) { Q = x + (size_t)b * N * 3; R = y + (size_t)b * M * 3; }
    else          { Q = y + (size_t)b * M * 3; R = x + (size_t)b * N * 3; }
    const int tid = threadIdx.x, q = tile * BQ + tid, base = split * 1024;
    for (int j = tid; j < 1024; j += BQ) {
        const float rx = R[(size_t)(base + j) * 3 + 0];
        const float ry = R[(size_t)(base + j) * 3 + 1];
        const float rz = R[(size_t)(base + j) * 3 + 2];
        sref[j] = make_float4(rx, ry, rz, 0.5f * (rx * rx + ry * ry + rz * rz));
    }
    __syncthreads();
    const float qx = Q[q * 3 + 0], qy = Q[q * 3 + 1], qz = Q[q * 3 + 2];
    float best = 3.4e38f; int bestj = base;
    #pragma unroll 8
    for (int j = 0; j < 1024; ++j) {
        const float4 r = sref[j];
        float t = __fmaf_rn(-qx, r.x, r.w);
        t = __fmaf_rn(-qy, r.y, t);
        t = __fmaf_rn(-qz, r.z, t);
        const bool c = t < best;
        best = c ? t : best; bestj = c ? (base + j) : bestj;
    }
    const size_t idx = ((size_t)dir * 8 + b) * (size_t)N + q;
    atomicMin(&packed[idx], ((unsigned long long)float_ord(best) << 32) | (unsigned int)bestj);
}

__global__ __launch_bounds__(BQ) void chamfer_gather_kernel(
    const float* __restrict__ x, const float* __restrict__ y,
    const unsigned long long* __restrict__ packed,
    float* __restrict__ acc, int N, int M)
{
    __shared__ float red[4];
    const int tid = threadIdx.x;
    const size_t gq = (size_t)blockIdx.x * BQ + tid;
    const int dir = (int)(gq / ((size_t)8 * N));
    const size_t rem = gq - (size_t)dir * 8 * N;
    const int b = (int)(rem / N), q = (int)(rem - (size_t)b * N);
    const float* Q; const float* R;
    if (dir == 0) { Q = x + (size_t)b * N * 3; R = y + (size_t)b * M * 3; }
    else          { Q = y + (size_t)b * M * 3; R = x + (size_t)b * N * 3; }
    const int j = (int)(unsigned int)packed[gq];
    const float dx = Q[q * 3 + 0] - R[(size_t)j * 3 + 0];
    const float dy = Q[q * 3 + 1] - R[(size_t)j * 3 + 1];
    const float dz = Q[q * 3 + 2] - R[(size_t)j * 3 + 2];
    const float ax = fabsf(dx), ay = fabsf(dy), az = fabsf(dz);
    const float ax2 = ax * ax, ay2 = ay * ay, az2 = az * az;
    float s = ax2 * ax2 * ax + ay2 * ay2 * ay + az2 * az2 * az;
    #pragma unroll
    for (int off = 32; off > 0; off >>= 1) s += __shfl_down(s, off, 64);
    const int wid = tid >> 6, lane = tid & 63;
    if (lane == 0) red[wid] = s;
    __syncthreads();
    if (tid == 0) atomicAdd(&acc[b * 2 + dir], red[0] + red[1] + red[2] + red[3]);
}

__global__ void chamfer_finalize_kernel(const float* __restrict__ acc,
                                        float* __restrict__ out)
{
    if (threadIdx.x == 0 && blockIdx.x == 0) {
        float total = 0.0f;
        #pragma unroll
        for (int i = 0; i < 16; ++i) total += powf(acc[i], 0.2f);
        *out = total * 0.125f;
    }
}

extern "C" void kernel_launch(void* const* d_in, const int* in_sizes, int n_in,
                              void* d_out, int out_size, void* d_ws, size_t ws_size,
                              hipStream_t stream)
{
    const float* x = (const float*)d_in[0];
    const float* y = (const float*)d_in[1];
    float* out = (float*)d_out;
    const int N = in_sizes[0] / 24;  // B=8, C=3
    const int M = in_sizes[1] / 24;

    const size_t needed = WS_TAB + (size_t)NQTOT * 8;  // ~528 KB

    if (N == 4096 && M == 4096 && ws_size >= needed) {
        unsigned char* ws = (unsigned char*)d_ws;
        unsigned long long* tab = (unsigned long long*)(ws + WS_TAB);
        unsigned int* tcnt = (unsigned int*)(ws + WS_TCNT);
        unsigned int* gcnt = (unsigned int*)(ws + WS_GCNT);
        const unsigned int* canary = (const unsigned int*)(ws + WS_CANARY);
        float* psum = (float*)(ws + WS_PSUM);
        chamfer_fused_r21<<<NTILE * SPLITS, BQ, 0, stream>>>(
            x, y, tab, tcnt, gcnt, canary, psum, out);
    } else {
        // round-2 proven path
        unsigned char* ws = (unsigned char*)d_ws;
        float* acc = (float*)ws;
        unsigned long long* ptab = (unsigned long long*)(ws + 4096);
        const size_t nQ = (size_t)2 * 8 * N;
        hipMemsetAsync(acc, 0, 64, stream);
        hipMemsetAsync(ptab, 0xFF, nQ * 8, stream);
        chamfer_nn_split_kernel<<<(int)(nQ / BQ) * 4, BQ, 0, stream>>>(x, y, ptab, N, M);
        chamfer_gather_kernel<<<(int)(nQ / BQ), BQ, 0, stream>>>(x, y, ptab, acc, N, M);
        chamfer_finalize_kernel<<<1, 64, 0, stream>>>(acc, out);
    }
}